// Round 8
// baseline (447.244 us; speedup 1.0000x reference)
//
#include <hip/hip_runtime.h>
#include <hip/hip_fp16.h>
#include <stdint.h>

// Problem constants (fixed by reference file)
#define TOKENS 65536   // T*B = 2048*32
#define D      128
#define NEXP   9       // MULTI_INFER_NUM + 1
#define MT     32      // tokens per tile; block = 4 waves, each 32 rows x 32 cols
#define MAXTILES (TOKENS / MT + NEXP)  // 2057
#define NHB    256     // assign blocks (TOKENS/256)

typedef _Float16 f16;
typedef _Float16 f16x8  __attribute__((ext_vector_type(8)));
typedef float    f32x4  __attribute__((ext_vector_type(4)));
typedef uint32_t u32;
typedef uint16_t u16;

// ---- workspace layout ----
// Within-expert token order is irrelevant, so fixed per-expert perm regions +
// atomicAdd reservation (capacities >15 sigma above expected expert counts).
#define WI_CNT      64                   // int index; 9 counters, stride 32 ints (128B apart)
#define ECAP_SMALL  8192
#define ECAP_BIG    49152
#define PERM_U16S   (8 * ECAP_SMALL + ECAP_BIG)   // 114688
#define WS_PERM_OFF 2048                 // bytes
#define WS_WF_OFF   (WS_PERM_OFF + PERM_U16S * 2) // 231424 (16B aligned)
// Wf: f16[72][16384] = 2359296 B; total ws usage ~2.47 MB

#define EBASE(E) ((E) < 8 ? ((E) << 13) : 65536)

#define LOG2E  1.44269504f

// ---- fused pre-kernel ----
// blocks 0..255   : expert assignment via per-wave ballot + one atomicAdd per
//                   (block, expert) reservation
// blocks 256..543 : fragment-major f16 weight conversion for 16x16x32:
//   Wf[mat][c(8)][kb(4)][lane(64)][i(8)], lane = quad*16 + n:
//     element = Ws[mat][d = kb*32 + quad*8 + i][f = c*16 + n]
__global__ void k_pre(const float* __restrict__ Ws, const int* __restrict__ pos,
                      int* __restrict__ wsI, u16* __restrict__ perm16,
                      f16* __restrict__ Wf) {
  const int tid = threadIdx.x;
  if (blockIdx.x >= 256) {
    const int bx  = blockIdx.x - 256;
    const int mat = bx >> 2;              // 0..71
    const int q   = bx & 3;
    const float* src = Ws + (size_t)mat * (D * D);
    f16* dst = Wf + (size_t)mat * (D * D);
#pragma unroll
    for (int p = 0; p < 2; ++p) {
      int cc = q * 512 + p * 256 + tid;   // 16B chunk index 0..2047 = ((c*4+kb)*64 + lane)
      int ln = cc & 63;
      int kb = (cc >> 6) & 3;
      int c  = cc >> 8;
      int quad = ln >> 4, n = ln & 15;
      int f  = c * 16 + n;
      int d0 = kb * 32 + quad * 8;
      f16x8 w;
#pragma unroll
      for (int i = 0; i < 8; ++i) w[i] = (f16)src[(d0 + i) * D + f];
      *(f16x8*)(dst + cc * 8) = w;
    }
  } else {
    const int b = blockIdx.x;
    const int lane = tid & 63, w = tid >> 6;
    __shared__ int waveCnt[4][NEXP];
    __shared__ int waveBase[4][NEXP];
    __shared__ int blockBase[NEXP];

    int e = pos[b * 256 + tid]; e = e < 8 ? e : 8;
    int myRank = 0;
#pragma unroll
    for (int ee = 0; ee < NEXP; ++ee) {
      unsigned long long m = __ballot(e == ee);
      if (e == ee) myRank = __popcll(m & ((1ull << lane) - 1ull));
      if (lane == 0) waveCnt[w][ee] = __popcll(m);
    }
    __syncthreads();
    if (tid < NEXP) {
      int s = 0;
#pragma unroll
      for (int w2 = 0; w2 < 4; ++w2) { waveBase[w2][tid] = s; s += waveCnt[w2][tid]; }
      blockBase[tid] = atomicAdd(&wsI[WI_CNT + tid * 32], s);  // device-scope
    }
    __syncthreads();
    perm16[EBASE(e) + blockBase[e] + waveBase[w][e] + myRank] = (u16)(b * 256 + tid);
  }
}

// ---- fused main: 16x16x32 MFMA; wave = 32 rows (2 subtiles) x 32 cols (2 chunks).
//      R3 body verbatim (2-buffer B rotation, bias folded into MFMA C-init,
//      fused-rcp epilogue, direct stores). ONE change: __launch_bounds__(256,8)
//      -> 8 blocks/CU (32 waves/CU) instead of the previous 16-wave cap; the
//      allocator already fit 64 VGPR, so the doubled wave pool is ~free and
//      attacks the measured latency-bound / under-occupied profile.
__launch_bounds__(256, 8)
__global__ void k_main(const float* __restrict__ xin, const float* __restrict__ bsPtr,
                       const int* __restrict__ wsI, const u16* __restrict__ perm16,
                       const f16* __restrict__ Wf, float* __restrict__ outPtr) {
  __shared__ __attribute__((aligned(16))) f16 Ash[MT][136];   // 32 x 272B (bank-safe)
  __shared__ int s_tok[MT];

  const int tid = threadIdx.x;
  const int bid = blockIdx.x;

  // tile -> (expert, token range) from expert counts
  int e = 0, tileOffE = 0, cntE = 0, to = 0;
#pragma unroll
  for (int ee = 0; ee < NEXP; ee++) {
    int c = wsI[WI_CNT + ee * 32];
    if (to <= bid) { e = ee; tileOffE = to; cntE = c; }
    to += (c + MT - 1) >> 5;
  }
  if (bid >= to) return;
  const int tokStart   = (bid - tileOffE) * MT;    // within expert region
  const int rowsValid  = min(MT, cntE - tokStart);
  const int permBase   = EBASE(e) + tokStart;

  const int lane = tid & 63;
  const int n    = lane & 15;       // MFMA col
  const int quad = lane >> 4;       // k-quad / row-quad
  const int cBase = (tid >> 6) * 2; // wave's first 16-col chunk (col-split across waves)
  const int vlane = lane * 8;       // B-frag lane offset (f16 elems)
  const f16* We = Wf + (size_t)e * 16384;   // mat stride = 9*16384 = 147456
  const int f0 = cBase * 16 + n;

  f16x8 aF0[4], aF1[4];             // A fragments: rows 0-15 / 16-31, full K=128
  f16x8 b0[4], b1[4];               // 2-buffer B rotation

#define PFB(BUF, LL, CC, JJ)                                                   \
  do {                                                                         \
    if ((LL) < 2) {                                                            \
      const f16* _p = We + ((LL) * 4 + (JJ)) * 147456 + (CC) * 2048 + vlane;   \
      _Pragma("unroll")                                                        \
      for (int _kb = 0; _kb < 4; ++_kb)                                        \
        BUF[_kb] = *(const f16x8*)(_p + _kb * 512);                            \
    }                                                                          \
  } while (0)

#define LOAD_AF()                                                              \
  do {                                                                         \
    _Pragma("unroll")                                                          \
    for (int _kb = 0; _kb < 4; ++_kb) {                                        \
      aF0[_kb] = *(const f16x8*)&Ash[n][_kb * 32 + quad * 8];                  \
      aF1[_kb] = *(const f16x8*)&Ash[16 + n][_kb * 32 + quad * 8];             \
    }                                                                          \
  } while (0)

#define MFMA2(G, BUF, BV)                                                      \
  do {                                                                         \
    f32x4 _x = {(BV), (BV), (BV), (BV)};                                       \
    f32x4 _y = _x;                                                             \
    _Pragma("unroll")                                                          \
    for (int _kb = 0; _kb < 4; ++_kb) {                                        \
      _x = __builtin_amdgcn_mfma_f32_16x16x32_f16(aF0[_kb], BUF[_kb], _x, 0, 0, 0); \
      _y = __builtin_amdgcn_mfma_f32_16x16x32_f16(aF1[_kb], BUF[_kb], _y, 0, 0, 0); \
    }                                                                          \
    acc[G][0] = _x; acc[G][1] = _y;                                            \
  } while (0)

  PFB(b0, 0, cBase, 0);   // stage (0,0) j0/j1 fly while we load bias + stage A
  PFB(b1, 0, cBase, 1);

  // ---- bias hoist: all 16 per-wave bias scalars, loaded once (L2-hot after block 0) ----
  float bias[2][2][4];
#pragma unroll
  for (int l = 0; l < 2; ++l)
#pragma unroll
    for (int ci = 0; ci < 2; ++ci)
#pragma unroll
      for (int j = 0; j < 4; ++j)
        bias[l][ci][j] = bsPtr[((l * 4 + j) * NEXP + e) * D + f0 + ci * 16];

  // ---- stage A (32 rows) as f16 via perm gather; zero-fill invalid rows ----
  {
    int m = tid >> 3, h = tid & 7;          // thread covers cols h*16..h*16+15
    bool valid = (m < rowsValid);
    int tok = 0;
    if (valid) tok = (int)perm16[permBase + m];
    if (h == 0) s_tok[m] = valid ? tok : -1;
    const float4* src = (const float4*)(xin + (size_t)tok * D + h * 16);
    f16* drow = &Ash[m][h * 16];
#pragma unroll
    for (int i = 0; i < 2; i++) {
      float4 a = make_float4(0.f, 0.f, 0.f, 0.f), b2v = a;
      if (valid) { a = src[2 * i]; b2v = src[2 * i + 1]; }
      f16x8 wv;
      wv[0] = (f16)a.x;   wv[1] = (f16)a.y;   wv[2] = (f16)a.z;   wv[3] = (f16)a.w;
      wv[4] = (f16)b2v.x; wv[5] = (f16)b2v.y; wv[6] = (f16)b2v.z; wv[7] = (f16)b2v.w;
      *(f16x8*)&drow[i * 8] = wv;
    }
  }
  __syncthreads();   // barrier 1: Ash staged
  LOAD_AF();
  __syncthreads();   // barrier 2: all waves' aF(l=0) loaded before any Ash overwrite

  // One (l,ci) stage: 2-buffer rotation; R3-proven schedule.
#define STAGE(L, CI, NL, NC)                                                   \
  do {                                                                         \
    const int cc = cBase + (CI);                                               \
    const int f = f0 + (CI) * 16;                                              \
    f32x4 acc[4][2];                                                           \
    PFB(b1, L, cc, 1);  MFMA2(0, b0, bias[L][CI][0]);                          \
    PFB(b0, L, cc, 2);  MFMA2(1, b1, bias[L][CI][1]);                          \
    PFB(b1, L, cc, 3);  MFMA2(2, b0, bias[L][CI][2]);                          \
    PFB(b0, NL, NC, 0); MFMA2(3, b1, bias[L][CI][3]);                          \
    /* ---- gating epilogue: batch LDS reads, then fused-rcp activation ---- */\
    float xv[2][4];                                                            \
    _Pragma("unroll")                                                          \
    for (int s = 0; s < 2; s++)                                                \
      _Pragma("unroll")                                                        \
      for (int r = 0; r < 4; r++)                                              \
        xv[s][r] = (float)Ash[s * 16 + quad * 4 + r][f];                       \
    _Pragma("unroll")                                                          \
    for (int s = 0; s < 2; s++) {                                              \
      _Pragma("unroll")                                                        \
      for (int r = 0; r < 4; r++) {                                            \
        int m = s * 16 + quad * 4 + r;        /* C/D row mapping (m89) */      \
        float sf = acc[0][s][r];              /* bias already in acc   */      \
        float lg = acc[1][s][r];                                               \
        float lf = acc[2][s][r];                                               \
        float of = acc[3][s][r];                                               \
        /* nr = x*sigm(sf) + tanh(lg)*sigm(lf), one rcp over common denom:  */ \
        float Ea = __builtin_amdgcn_exp2f(-LOG2E * sf);                        \
        float Eb = __builtin_amdgcn_exp2f((2.0f * LOG2E) * lg);                \
        float Ec = __builtin_amdgcn_exp2f(-LOG2E * lf);                        \
        float d1 = 1.0f + Ea, d2 = Eb + 1.0f, d3 = 1.0f + Ec;                  \
        float p23 = d2 * d3;                                                   \
        float nr = (xv[s][r] * p23 + (d2 - 2.0f) * d1) *                       \
                   __builtin_amdgcn_rcpf(d1 * p23);                            \
        float Ed = __builtin_amdgcn_exp2f((2.0f * LOG2E) * nr);                \
        float Ee = __builtin_amdgcn_exp2f(-LOG2E * of);                        \
        float xn = (Ed - 1.0f) * __builtin_amdgcn_rcpf((Ed + 1.0f) * (1.0f + Ee)); \
        if ((L) == 0) {                                                        \
          Ash[m][f] = (f16)xn;                  /* layer-1 input (own cols) */ \
        } else {                                                               \
          int tok = s_tok[m];                                                  \
          if (tok >= 0) outPtr[(size_t)tok * D + f] = xn;                      \
        }                                                                      \
      }                                                                        \
    }                                                                          \
  } while (0)

  STAGE(0, 0, 0, cBase + 1);
  STAGE(0, 1, 1, cBase);
  __syncthreads();            // barrier 3: all waves' l=0 Ash writes done
  LOAD_AF();                  // reload full-K A fragments for layer 1
  STAGE(1, 0, 1, cBase + 1);
  STAGE(1, 1, 2, 0);          // NL=2 -> trailing PFB folds away

#undef STAGE
#undef MFMA2
#undef LOAD_AF
#undef PFB
}

extern "C" void kernel_launch(void* const* d_in, const int* in_sizes, int n_in,
                              void* d_out, int out_size, void* d_ws, size_t ws_size,
                              hipStream_t stream) {
  const int*   pos = (const int*)d_in[0];
  const float* x   = (const float*)d_in[1];
  const float* Ws  = (const float*)d_in[2];
  const float* bs  = (const float*)d_in[3];
  float* out = (float*)d_out;
  int* wsI = (int*)d_ws;
  u16* perm16 = (u16*)((char*)d_ws + WS_PERM_OFF);
  f16* Wf = (f16*)((char*)d_ws + WS_WF_OFF);

  hipMemsetAsync((char*)d_ws + WI_CNT * 4, 0, NEXP * 32 * 4, stream);  // zero counters
  k_pre <<<544, 256, 0, stream>>>(Ws, pos, wsI, perm16, Wf);
  k_main<<<MAXTILES, 256, 0, stream>>>(x, bs, wsI, perm16, Wf, out);
}

// Round 9
// 129.773 us; speedup vs baseline: 3.4464x; 3.4464x over previous
//
#include <hip/hip_runtime.h>
#include <hip/hip_fp16.h>
#include <stdint.h>

// Problem constants (fixed by reference file)
#define TOKENS 65536   // T*B = 2048*32
#define D      128
#define NEXP   9       // MULTI_INFER_NUM + 1
#define MT     32      // tokens per tile; block = 4 waves, each 32 rows x 32 cols
#define MAXTILES (TOKENS / MT + NEXP)  // 2057
#define NHB    256     // assign blocks (TOKENS/256)

typedef _Float16 f16;
typedef _Float16 f16x8  __attribute__((ext_vector_type(8)));
typedef float    f32x4  __attribute__((ext_vector_type(4)));
typedef uint32_t u32;
typedef uint16_t u16;

// ---- workspace layout ----
// Within-expert token order is irrelevant, so fixed per-expert perm regions +
// atomicAdd reservation (capacities >15 sigma above expected expert counts).
#define WI_CNT      64                   // int index; 9 counters, stride 32 ints (128B apart)
#define ECAP_SMALL  8192
#define ECAP_BIG    49152
#define PERM_U16S   (8 * ECAP_SMALL + ECAP_BIG)   // 114688
#define WS_PERM_OFF 2048                 // bytes
#define WS_WF_OFF   (WS_PERM_OFF + PERM_U16S * 2) // 231424 (16B aligned)
// Wf: f16[72][16384] = 2359296 B; total ws usage ~2.47 MB

#define EBASE(E) ((E) < 8 ? ((E) << 13) : 65536)

#define LOG2E  1.44269504f

// ---- fused pre-kernel ----
// blocks 0..255   : expert assignment via per-wave ballot + one atomicAdd per
//                   (block, expert) reservation
// blocks 256..543 : fragment-major f16 weight conversion for 16x16x32:
//   Wf[mat][c(8)][kb(4)][lane(64)][i(8)], lane = quad*16 + n:
//     element = Ws[mat][d = kb*32 + quad*8 + i][f = c*16 + n]
__global__ void k_pre(const float* __restrict__ Ws, const int* __restrict__ pos,
                      int* __restrict__ wsI, u16* __restrict__ perm16,
                      f16* __restrict__ Wf) {
  const int tid = threadIdx.x;
  if (blockIdx.x >= 256) {
    const int bx  = blockIdx.x - 256;
    const int mat = bx >> 2;              // 0..71
    const int q   = bx & 3;
    const float* src = Ws + (size_t)mat * (D * D);
    f16* dst = Wf + (size_t)mat * (D * D);
#pragma unroll
    for (int p = 0; p < 2; ++p) {
      int cc = q * 512 + p * 256 + tid;   // 16B chunk index 0..2047 = ((c*4+kb)*64 + lane)
      int ln = cc & 63;
      int kb = (cc >> 6) & 3;
      int c  = cc >> 8;
      int quad = ln >> 4, n = ln & 15;
      int f  = c * 16 + n;
      int d0 = kb * 32 + quad * 8;
      f16x8 w;
#pragma unroll
      for (int i = 0; i < 8; ++i) w[i] = (f16)src[(d0 + i) * D + f];
      *(f16x8*)(dst + cc * 8) = w;
    }
  } else {
    const int b = blockIdx.x;
    const int lane = tid & 63, w = tid >> 6;
    __shared__ int waveCnt[4][NEXP];
    __shared__ int waveBase[4][NEXP];
    __shared__ int blockBase[NEXP];

    int e = pos[b * 256 + tid]; e = e < 8 ? e : 8;
    int myRank = 0;
#pragma unroll
    for (int ee = 0; ee < NEXP; ++ee) {
      unsigned long long m = __ballot(e == ee);
      if (e == ee) myRank = __popcll(m & ((1ull << lane) - 1ull));
      if (lane == 0) waveCnt[w][ee] = __popcll(m);
    }
    __syncthreads();
    if (tid < NEXP) {
      int s = 0;
#pragma unroll
      for (int w2 = 0; w2 < 4; ++w2) { waveBase[w2][tid] = s; s += waveCnt[w2][tid]; }
      blockBase[tid] = atomicAdd(&wsI[WI_CNT + tid * 32], s);  // device-scope
    }
    __syncthreads();
    perm16[EBASE(e) + blockBase[e] + waveBase[w][e] + myRank] = (u16)(b * 256 + tid);
  }
}

// ---- fused main: 16x16x32 MFMA; wave = 32 rows (2 subtiles) x 32 cols (2 chunks).
//      R3 body verbatim (best verified: 125.49 us total, VGPR 64, no spill):
//      2-buffer B rotation, bias folded into MFMA C-init, fused-rcp epilogue
//      (7 trans/element), direct global stores. ONE added lever: s_setprio(1/0)
//      around each 8-MFMA cluster (T5 positive regime: independent blocks at
//      different phases, cf. attn m191 +4-7%).
//      NOTE (R8 lesson): gfx950 unified VGPR+AGPR file -> this kernel's true
//      footprint is ~64 VGPR + 32 acc = ~96 regs/wave (~5 blocks/CU resident).
//      __launch_bounds__(256,8) forces 64 total -> catastrophic spill. Keep (256,4).
__launch_bounds__(256, 4)
__global__ void k_main(const float* __restrict__ xin, const float* __restrict__ bsPtr,
                       const int* __restrict__ wsI, const u16* __restrict__ perm16,
                       const f16* __restrict__ Wf, float* __restrict__ outPtr) {
  __shared__ __attribute__((aligned(16))) f16 Ash[MT][136];   // 32 x 272B (bank-safe)
  __shared__ int s_tok[MT];

  const int tid = threadIdx.x;
  const int bid = blockIdx.x;

  // tile -> (expert, token range) from expert counts
  int e = 0, tileOffE = 0, cntE = 0, to = 0;
#pragma unroll
  for (int ee = 0; ee < NEXP; ee++) {
    int c = wsI[WI_CNT + ee * 32];
    if (to <= bid) { e = ee; tileOffE = to; cntE = c; }
    to += (c + MT - 1) >> 5;
  }
  if (bid >= to) return;
  const int tokStart   = (bid - tileOffE) * MT;    // within expert region
  const int rowsValid  = min(MT, cntE - tokStart);
  const int permBase   = EBASE(e) + tokStart;

  const int lane = tid & 63;
  const int n    = lane & 15;       // MFMA col
  const int quad = lane >> 4;       // k-quad / row-quad
  const int cBase = (tid >> 6) * 2; // wave's first 16-col chunk (col-split across waves)
  const int vlane = lane * 8;       // B-frag lane offset (f16 elems)
  const f16* We = Wf + (size_t)e * 16384;   // mat stride = 9*16384 = 147456
  const int f0 = cBase * 16 + n;

  f16x8 aF0[4], aF1[4];             // A fragments: rows 0-15 / 16-31, full K=128
  f16x8 b0[4], b1[4];               // 2-buffer B rotation

#define PFB(BUF, LL, CC, JJ)                                                   \
  do {                                                                         \
    if ((LL) < 2) {                                                            \
      const f16* _p = We + ((LL) * 4 + (JJ)) * 147456 + (CC) * 2048 + vlane;   \
      _Pragma("unroll")                                                        \
      for (int _kb = 0; _kb < 4; ++_kb)                                        \
        BUF[_kb] = *(const f16x8*)(_p + _kb * 512);                            \
    }                                                                          \
  } while (0)

#define LOAD_AF()                                                              \
  do {                                                                         \
    _Pragma("unroll")                                                          \
    for (int _kb = 0; _kb < 4; ++_kb) {                                        \
      aF0[_kb] = *(const f16x8*)&Ash[n][_kb * 32 + quad * 8];                  \
      aF1[_kb] = *(const f16x8*)&Ash[16 + n][_kb * 32 + quad * 8];             \
    }                                                                          \
  } while (0)

#define MFMA2(G, BUF, BV)                                                      \
  do {                                                                         \
    f32x4 _x = {(BV), (BV), (BV), (BV)};                                       \
    f32x4 _y = _x;                                                             \
    __builtin_amdgcn_s_setprio(1);                                             \
    _Pragma("unroll")                                                          \
    for (int _kb = 0; _kb < 4; ++_kb) {                                        \
      _x = __builtin_amdgcn_mfma_f32_16x16x32_f16(aF0[_kb], BUF[_kb], _x, 0, 0, 0); \
      _y = __builtin_amdgcn_mfma_f32_16x16x32_f16(aF1[_kb], BUF[_kb], _y, 0, 0, 0); \
    }                                                                          \
    __builtin_amdgcn_s_setprio(0);                                             \
    acc[G][0] = _x; acc[G][1] = _y;                                            \
  } while (0)

  PFB(b0, 0, cBase, 0);   // stage (0,0) j0/j1 fly while we load bias + stage A
  PFB(b1, 0, cBase, 1);

  // ---- bias hoist: all 16 per-wave bias scalars, loaded once (L2-hot after block 0) ----
  float bias[2][2][4];
#pragma unroll
  for (int l = 0; l < 2; ++l)
#pragma unroll
    for (int ci = 0; ci < 2; ++ci)
#pragma unroll
      for (int j = 0; j < 4; ++j)
        bias[l][ci][j] = bsPtr[((l * 4 + j) * NEXP + e) * D + f0 + ci * 16];

  // ---- stage A (32 rows) as f16 via perm gather; zero-fill invalid rows ----
  {
    int m = tid >> 3, h = tid & 7;          // thread covers cols h*16..h*16+15
    bool valid = (m < rowsValid);
    int tok = 0;
    if (valid) tok = (int)perm16[permBase + m];
    if (h == 0) s_tok[m] = valid ? tok : -1;
    const float4* src = (const float4*)(xin + (size_t)tok * D + h * 16);
    f16* drow = &Ash[m][h * 16];
#pragma unroll
    for (int i = 0; i < 2; i++) {
      float4 a = make_float4(0.f, 0.f, 0.f, 0.f), b2v = a;
      if (valid) { a = src[2 * i]; b2v = src[2 * i + 1]; }
      f16x8 wv;
      wv[0] = (f16)a.x;   wv[1] = (f16)a.y;   wv[2] = (f16)a.z;   wv[3] = (f16)a.w;
      wv[4] = (f16)b2v.x; wv[5] = (f16)b2v.y; wv[6] = (f16)b2v.z; wv[7] = (f16)b2v.w;
      *(f16x8*)&drow[i * 8] = wv;
    }
  }
  __syncthreads();   // barrier 1: Ash staged
  LOAD_AF();
  __syncthreads();   // barrier 2: all waves' aF(l=0) loaded before any Ash overwrite

  // One (l,ci) stage: 2-buffer rotation; R3-proven schedule.
#define STAGE(L, CI, NL, NC)                                                   \
  do {                                                                         \
    const int cc = cBase + (CI);                                               \
    const int f = f0 + (CI) * 16;                                              \
    f32x4 acc[4][2];                                                           \
    PFB(b1, L, cc, 1);  MFMA2(0, b0, bias[L][CI][0]);                          \
    PFB(b0, L, cc, 2);  MFMA2(1, b1, bias[L][CI][1]);                          \
    PFB(b1, L, cc, 3);  MFMA2(2, b0, bias[L][CI][2]);                          \
    PFB(b0, NL, NC, 0); MFMA2(3, b1, bias[L][CI][3]);                          \
    /* ---- gating epilogue: batch LDS reads, then fused-rcp activation ---- */\
    float xv[2][4];                                                            \
    _Pragma("unroll")                                                          \
    for (int s = 0; s < 2; s++)                                                \
      _Pragma("unroll")                                                        \
      for (int r = 0; r < 4; r++)                                              \
        xv[s][r] = (float)Ash[s * 16 + quad * 4 + r][f];                       \
    _Pragma("unroll")                                                          \
    for (int s = 0; s < 2; s++) {                                              \
      _Pragma("unroll")                                                        \
      for (int r = 0; r < 4; r++) {                                            \
        int m = s * 16 + quad * 4 + r;        /* C/D row mapping (m89) */      \
        float sf = acc[0][s][r];              /* bias already in acc   */      \
        float lg = acc[1][s][r];                                               \
        float lf = acc[2][s][r];                                               \
        float of = acc[3][s][r];                                               \
        /* nr = x*sigm(sf) + tanh(lg)*sigm(lf), one rcp over common denom:  */ \
        float Ea = __builtin_amdgcn_exp2f(-LOG2E * sf);                        \
        float Eb = __builtin_amdgcn_exp2f((2.0f * LOG2E) * lg);                \
        float Ec = __builtin_amdgcn_exp2f(-LOG2E * lf);                        \
        float d1 = 1.0f + Ea, d2 = Eb + 1.0f, d3 = 1.0f + Ec;                  \
        float p23 = d2 * d3;                                                   \
        float nr = (xv[s][r] * p23 + (d2 - 2.0f) * d1) *                       \
                   __builtin_amdgcn_rcpf(d1 * p23);                            \
        float Ed = __builtin_amdgcn_exp2f((2.0f * LOG2E) * nr);                \
        float Ee = __builtin_amdgcn_exp2f(-LOG2E * of);                        \
        float xn = (Ed - 1.0f) * __builtin_amdgcn_rcpf((Ed + 1.0f) * (1.0f + Ee)); \
        if ((L) == 0) {                                                        \
          Ash[m][f] = (f16)xn;                  /* layer-1 input (own cols) */ \
        } else {                                                               \
          int tok = s_tok[m];                                                  \
          if (tok >= 0) outPtr[(size_t)tok * D + f] = xn;                      \
        }                                                                      \
      }                                                                        \
    }                                                                          \
  } while (0)

  STAGE(0, 0, 0, cBase + 1);
  STAGE(0, 1, 1, cBase);
  __syncthreads();            // barrier 3: all waves' l=0 Ash writes done
  LOAD_AF();                  // reload full-K A fragments for layer 1
  STAGE(1, 0, 1, cBase + 1);
  STAGE(1, 1, 2, 0);          // NL=2 -> trailing PFB folds away

#undef STAGE
#undef MFMA2
#undef LOAD_AF
#undef PFB
}

extern "C" void kernel_launch(void* const* d_in, const int* in_sizes, int n_in,
                              void* d_out, int out_size, void* d_ws, size_t ws_size,
                              hipStream_t stream) {
  const int*   pos = (const int*)d_in[0];
  const float* x   = (const float*)d_in[1];
  const float* Ws  = (const float*)d_in[2];
  const float* bs  = (const float*)d_in[3];
  float* out = (float*)d_out;
  int* wsI = (int*)d_ws;
  u16* perm16 = (u16*)((char*)d_ws + WS_PERM_OFF);
  f16* Wf = (f16*)((char*)d_ws + WS_WF_OFF);

  hipMemsetAsync((char*)d_ws + WI_CNT * 4, 0, NEXP * 32 * 4, stream);  // zero counters
  k_pre <<<544, 256, 0, stream>>>(Ws, pos, wsI, perm16, Wf);
  k_main<<<MAXTILES, 256, 0, stream>>>(x, bs, wsI, perm16, Wf, out);
}

// Round 10
// 124.355 us; speedup vs baseline: 3.5965x; 1.0436x over previous
//
#include <hip/hip_runtime.h>
#include <hip/hip_fp16.h>
#include <stdint.h>

// Problem constants (fixed by reference file)
#define TOKENS 65536   // T*B = 2048*32
#define D      128
#define NEXP   9       // MULTI_INFER_NUM + 1
#define MT     32      // tokens per tile; block = 4 waves, each 32 rows x 32 cols
#define MAXTILES (TOKENS / MT + NEXP)  // 2057

typedef _Float16 f16;
typedef _Float16 f16x8  __attribute__((ext_vector_type(8)));
typedef float    f32x4  __attribute__((ext_vector_type(4)));
typedef uint32_t u32;
typedef uint16_t u16;

// ---- workspace layout ----
// Within-expert token order is irrelevant, so fixed per-expert perm regions +
// atomicAdd reservation (capacities >15 sigma above expected expert counts).
#define WI_CNT      64                   // int index; 9 counters, stride 32 ints (128B apart)
#define ECAP_SMALL  8192
#define ECAP_BIG    49152
#define PERM_U16S   (8 * ECAP_SMALL + ECAP_BIG)   // 114688
#define WS_PERM_OFF 2048                 // bytes
#define WS_WF_OFF   (WS_PERM_OFF + PERM_U16S * 2) // 231424 (16B aligned)
// Wf: f16[72][16384] = 2359296 B; total ws usage ~2.47 MB

#define EBASE(E) ((E) < 8 ? ((E) << 13) : 65536)

#define LOG2E  1.44269504f

// ---- fused pre-kernel ----
// blocks 0..255   : expert assignment via per-wave ballot + one atomicAdd per
//                   (block, expert) reservation
// blocks 256..543 : fragment-major f16 weight conversion for 16x16x32:
//   Wf[mat][c(8)][kb(4)][lane(64)][i(8)], lane = quad*16 + n:
//     element = Ws[mat][d = kb*32 + quad*8 + i][f = c*16 + n]
__global__ void k_pre(const float* __restrict__ Ws, const int* __restrict__ pos,
                      int* __restrict__ wsI, u16* __restrict__ perm16,
                      f16* __restrict__ Wf) {
  const int tid = threadIdx.x;
  if (blockIdx.x >= 256) {
    const int bx  = blockIdx.x - 256;
    const int mat = bx >> 2;              // 0..71
    const int q   = bx & 3;
    const float* src = Ws + (size_t)mat * (D * D);
    f16* dst = Wf + (size_t)mat * (D * D);
#pragma unroll
    for (int p = 0; p < 2; ++p) {
      int cc = q * 512 + p * 256 + tid;   // 16B chunk index 0..2047 = ((c*4+kb)*64 + lane)
      int ln = cc & 63;
      int kb = (cc >> 6) & 3;
      int c  = cc >> 8;
      int quad = ln >> 4, n = ln & 15;
      int f  = c * 16 + n;
      int d0 = kb * 32 + quad * 8;
      f16x8 w;
#pragma unroll
      for (int i = 0; i < 8; ++i) w[i] = (f16)src[(d0 + i) * D + f];
      *(f16x8*)(dst + cc * 8) = w;
    }
  } else {
    const int b = blockIdx.x;
    const int lane = tid & 63, w = tid >> 6;
    __shared__ int waveCnt[4][NEXP];
    __shared__ int waveBase[4][NEXP];
    __shared__ int blockBase[NEXP];

    int e = pos[b * 256 + tid]; e = e < 8 ? e : 8;
    int myRank = 0;
#pragma unroll
    for (int ee = 0; ee < NEXP; ++ee) {
      unsigned long long m = __ballot(e == ee);
      if (e == ee) myRank = __popcll(m & ((1ull << lane) - 1ull));
      if (lane == 0) waveCnt[w][ee] = __popcll(m);
    }
    __syncthreads();
    if (tid < NEXP) {
      int s = 0;
#pragma unroll
      for (int w2 = 0; w2 < 4; ++w2) { waveBase[w2][tid] = s; s += waveCnt[w2][tid]; }
      blockBase[tid] = atomicAdd(&wsI[WI_CNT + tid * 32], s);  // device-scope
    }
    __syncthreads();
    perm16[EBASE(e) + blockBase[e] + waveBase[w][e] + myRank] = (u16)(b * 256 + tid);
  }
}

// ---- fused main: 16x16x32 MFMA; wave = 32 rows (2 subtiles) x 32 cols (2 chunks).
//      Best verified configuration (R3: 125.49 us total, k_main ~45.7 us, VGPR 64,
//      no spill): 2-buffer B rotation, bias folded into MFMA C-init, fused-rcp
//      gating epilogue (7 transcendentals/element), direct global stores.
//      Session findings baked in:
//      * gfx950 unified VGPR+AGPR file: true footprint ~64 VGPR + 32 acc = ~96/wave
//        (~5 blocks/CU resident). __launch_bounds__(256,8) forces 64 total ->
//        catastrophic spill (R8: 370 us). Keep (256,4).
//      * Invariant to B-pipeline depth 1/2/3, cross-tile prefetch, MT=64,
//        store granularity, setprio (R3/R4/R6/R7/R9 nulls) -- latency plateau
//        of this structure; only arithmetic-work reduction moved it (R2).
__launch_bounds__(256, 4)
__global__ void k_main(const float* __restrict__ xin, const float* __restrict__ bsPtr,
                       const int* __restrict__ wsI, const u16* __restrict__ perm16,
                       const f16* __restrict__ Wf, float* __restrict__ outPtr) {
  __shared__ __attribute__((aligned(16))) f16 Ash[MT][136];   // 32 x 272B (bank-safe)
  __shared__ int s_tok[MT];

  const int tid = threadIdx.x;
  const int bid = blockIdx.x;

  // tile -> (expert, token range) from expert counts
  int e = 0, tileOffE = 0, cntE = 0, to = 0;
#pragma unroll
  for (int ee = 0; ee < NEXP; ee++) {
    int c = wsI[WI_CNT + ee * 32];
    if (to <= bid) { e = ee; tileOffE = to; cntE = c; }
    to += (c + MT - 1) >> 5;
  }
  if (bid >= to) return;
  const int tokStart   = (bid - tileOffE) * MT;    // within expert region
  const int rowsValid  = min(MT, cntE - tokStart);
  const int permBase   = EBASE(e) + tokStart;

  const int lane = tid & 63;
  const int n    = lane & 15;       // MFMA col
  const int quad = lane >> 4;       // k-quad / row-quad
  const int cBase = (tid >> 6) * 2; // wave's first 16-col chunk (col-split across waves)
  const int vlane = lane * 8;       // B-frag lane offset (f16 elems)
  const f16* We = Wf + (size_t)e * 16384;   // mat stride = 9*16384 = 147456
  const int f0 = cBase * 16 + n;

  f16x8 aF0[4], aF1[4];             // A fragments: rows 0-15 / 16-31, full K=128
  f16x8 b0[4], b1[4];               // 2-buffer B rotation

#define PFB(BUF, LL, CC, JJ)                                                   \
  do {                                                                         \
    if ((LL) < 2) {                                                            \
      const f16* _p = We + ((LL) * 4 + (JJ)) * 147456 + (CC) * 2048 + vlane;   \
      _Pragma("unroll")                                                        \
      for (int _kb = 0; _kb < 4; ++_kb)                                        \
        BUF[_kb] = *(const f16x8*)(_p + _kb * 512);                            \
    }                                                                          \
  } while (0)

#define LOAD_AF()                                                              \
  do {                                                                         \
    _Pragma("unroll")                                                          \
    for (int _kb = 0; _kb < 4; ++_kb) {                                        \
      aF0[_kb] = *(const f16x8*)&Ash[n][_kb * 32 + quad * 8];                  \
      aF1[_kb] = *(const f16x8*)&Ash[16 + n][_kb * 32 + quad * 8];             \
    }                                                                          \
  } while (0)

#define MFMA2(G, BUF, BV)                                                      \
  do {                                                                         \
    f32x4 _x = {(BV), (BV), (BV), (BV)};                                       \
    f32x4 _y = _x;                                                             \
    _Pragma("unroll")                                                          \
    for (int _kb = 0; _kb < 4; ++_kb) {                                        \
      _x = __builtin_amdgcn_mfma_f32_16x16x32_f16(aF0[_kb], BUF[_kb], _x, 0, 0, 0); \
      _y = __builtin_amdgcn_mfma_f32_16x16x32_f16(aF1[_kb], BUF[_kb], _y, 0, 0, 0); \
    }                                                                          \
    acc[G][0] = _x; acc[G][1] = _y;                                            \
  } while (0)

  PFB(b0, 0, cBase, 0);   // stage (0,0) j0/j1 fly while we load bias + stage A
  PFB(b1, 0, cBase, 1);

  // ---- bias hoist: all 16 per-wave bias scalars, loaded once (L2-hot after block 0) ----
  float bias[2][2][4];
#pragma unroll
  for (int l = 0; l < 2; ++l)
#pragma unroll
    for (int ci = 0; ci < 2; ++ci)
#pragma unroll
      for (int j = 0; j < 4; ++j)
        bias[l][ci][j] = bsPtr[((l * 4 + j) * NEXP + e) * D + f0 + ci * 16];

  // ---- stage A (32 rows) as f16 via perm gather; zero-fill invalid rows ----
  {
    int m = tid >> 3, h = tid & 7;          // thread covers cols h*16..h*16+15
    bool valid = (m < rowsValid);
    int tok = 0;
    if (valid) tok = (int)perm16[permBase + m];
    if (h == 0) s_tok[m] = valid ? tok : -1;
    const float4* src = (const float4*)(xin + (size_t)tok * D + h * 16);
    f16* drow = &Ash[m][h * 16];
#pragma unroll
    for (int i = 0; i < 2; i++) {
      float4 a = make_float4(0.f, 0.f, 0.f, 0.f), b2v = a;
      if (valid) { a = src[2 * i]; b2v = src[2 * i + 1]; }
      f16x8 wv;
      wv[0] = (f16)a.x;   wv[1] = (f16)a.y;   wv[2] = (f16)a.z;   wv[3] = (f16)a.w;
      wv[4] = (f16)b2v.x; wv[5] = (f16)b2v.y; wv[6] = (f16)b2v.z; wv[7] = (f16)b2v.w;
      *(f16x8*)&drow[i * 8] = wv;
    }
  }
  __syncthreads();   // barrier 1: Ash staged
  LOAD_AF();
  __syncthreads();   // barrier 2: all waves' aF(l=0) loaded before any Ash overwrite

  // One (l,ci) stage: 2-buffer rotation; proven schedule.
#define STAGE(L, CI, NL, NC)                                                   \
  do {                                                                         \
    const int cc = cBase + (CI);                                               \
    const int f = f0 + (CI) * 16;                                              \
    f32x4 acc[4][2];                                                           \
    PFB(b1, L, cc, 1);  MFMA2(0, b0, bias[L][CI][0]);                          \
    PFB(b0, L, cc, 2);  MFMA2(1, b1, bias[L][CI][1]);                          \
    PFB(b1, L, cc, 3);  MFMA2(2, b0, bias[L][CI][2]);                          \
    PFB(b0, NL, NC, 0); MFMA2(3, b1, bias[L][CI][3]);                          \
    /* ---- gating epilogue: batch LDS reads, then fused-rcp activation ---- */\
    float xv[2][4];                                                            \
    _Pragma("unroll")                                                          \
    for (int s = 0; s < 2; s++)                                                \
      _Pragma("unroll")                                                        \
      for (int r = 0; r < 4; r++)                                              \
        xv[s][r] = (float)Ash[s * 16 + quad * 4 + r][f];                       \
    _Pragma("unroll")                                                          \
    for (int s = 0; s < 2; s++) {                                              \
      _Pragma("unroll")                                                        \
      for (int r = 0; r < 4; r++) {                                            \
        int m = s * 16 + quad * 4 + r;        /* C/D row mapping (m89) */      \
        float sf = acc[0][s][r];              /* bias already in acc   */      \
        float lg = acc[1][s][r];                                               \
        float lf = acc[2][s][r];                                               \
        float of = acc[3][s][r];                                               \
        /* nr = x*sigm(sf) + tanh(lg)*sigm(lf), one rcp over common denom:  */ \
        /*   Ea=e^-sf, Eb=e^{2lg}, Ec=e^-lf                                 */ \
        /*   nr = [x*(Eb+1)(1+Ec) + (Eb-1)(1+Ea)] / [(1+Ea)(Eb+1)(1+Ec)]    */ \
        float Ea = __builtin_amdgcn_exp2f(-LOG2E * sf);                        \
        float Eb = __builtin_amdgcn_exp2f((2.0f * LOG2E) * lg);                \
        float Ec = __builtin_amdgcn_exp2f(-LOG2E * lf);                        \
        float d1 = 1.0f + Ea, d2 = Eb + 1.0f, d3 = 1.0f + Ec;                  \
        float p23 = d2 * d3;                                                   \
        float nr = (xv[s][r] * p23 + (d2 - 2.0f) * d1) *                       \
                   __builtin_amdgcn_rcpf(d1 * p23);                            \
        /* out = tanh(nr)*sigm(of) = (Ed-1) / [(Ed+1)(1+Ee)] */                \
        float Ed = __builtin_amdgcn_exp2f((2.0f * LOG2E) * nr);                \
        float Ee = __builtin_amdgcn_exp2f(-LOG2E * of);                        \
        float xn = (Ed - 1.0f) * __builtin_amdgcn_rcpf((Ed + 1.0f) * (1.0f + Ee)); \
        if ((L) == 0) {                                                        \
          Ash[m][f] = (f16)xn;                  /* layer-1 input (own cols) */ \
        } else {                                                               \
          int tok = s_tok[m];                                                  \
          if (tok >= 0) outPtr[(size_t)tok * D + f] = xn;                      \
        }                                                                      \
      }                                                                        \
    }                                                                          \
  } while (0)

  STAGE(0, 0, 0, cBase + 1);
  STAGE(0, 1, 1, cBase);
  __syncthreads();            // barrier 3: all waves' l=0 Ash writes done
  LOAD_AF();                  // reload full-K A fragments for layer 1
  STAGE(1, 0, 1, cBase + 1);
  STAGE(1, 1, 2, 0);          // NL=2 -> trailing PFB folds away

#undef STAGE
#undef MFMA2
#undef LOAD_AF
#undef PFB
}

extern "C" void kernel_launch(void* const* d_in, const int* in_sizes, int n_in,
                              void* d_out, int out_size, void* d_ws, size_t ws_size,
                              hipStream_t stream) {
  const int*   pos = (const int*)d_in[0];
  const float* x   = (const float*)d_in[1];
  const float* Ws  = (const float*)d_in[2];
  const float* bs  = (const float*)d_in[3];
  float* out = (float*)d_out;
  int* wsI = (int*)d_ws;
  u16* perm16 = (u16*)((char*)d_ws + WS_PERM_OFF);
  f16* Wf = (f16*)((char*)d_ws + WS_WF_OFF);

  hipMemsetAsync((char*)d_ws + WI_CNT * 4, 0, NEXP * 32 * 4, stream);  // zero counters
  k_pre <<<544, 256, 0, stream>>>(Ws, pos, wsI, perm16, Wf);
  k_main<<<MAXTILES, 256, 0, stream>>>(x, bs, wsI, perm16, Wf, out);
}